// Round 17
// baseline (53.013 us; speedup 1.0000x reference)
//
#include <hip/hip_runtime.h>
#include <math.h>

#define C2 2.8853900817779268f   // 2*log2(e)

typedef __attribute__((address_space(3))) unsigned int       lds_u32;
typedef const __attribute__((address_space(1))) unsigned int g_u32;

__device__ __forceinline__ void stage16(const float* g, float* l) {
    __builtin_amdgcn_global_load_lds((g_u32*)g, (lds_u32*)l, 16, 0, 0);
}

// prep: ekt[b][t4][g32][k64][hi4] = exp2(C2 * K[b][k=t*64+k64][h=4g+hi])
__global__ __launch_bounds__(512) void addattn_prep(const float* __restrict__ k_g,
                                                    float* __restrict__ ekt)
{
    int tid = blockIdx.x * 512 + threadIdx.x;   // 262144
    int b   = tid >> 13;
    int r   = tid & 8191;
    int g   = r >> 8;           // h-chunk of 4 (0..31)
    int k   = r & 255;
    float4 kv = *(const float4*)(k_g + ((size_t)(b * 256 + k)) * 128 + (g << 2));
    float4 E;
    E.x = __builtin_amdgcn_exp2f(C2 * kv.x);
    E.y = __builtin_amdgcn_exp2f(C2 * kv.y);
    E.z = __builtin_amdgcn_exp2f(C2 * kv.z);
    E.w = __builtin_amdgcn_exp2f(C2 * kv.w);
    *(float4*)(ekt + (size_t)b * 32768 + ((k >> 6) << 13) + (g << 8) + ((k & 63) << 2)) = E;
}

// main: 256 blocks x 1024 thr (16 waves = 4/SIMD at 1 block/CU).
// Block = (batch, 32 q rows); wave = 2 rows. All of ekt[b] LDS-resident.
// Per-wave 2KB strip: {Eq[2][128], w[128]} during score -> attn[2][256] after.
// ONE barrier (post-stage). No barrier after score: strips are wave-private,
// kbuf is read-only -> waves pipeline score/softmax/PV independently.
__global__ __launch_bounds__(1024, 4) void addattn_kernel(
    const float* __restrict__ q_g, const float* __restrict__ ekt,
    const float* __restrict__ v_g, const float* __restrict__ w_g,
    float* __restrict__ out)
{
    __shared__ float kbuf[32768];   // 128 KB: ekt[b] [t][g][k64][hi]
    __shared__ float sB[8192];      //  32 KB: 16 waves x 512-float strip

    const int tid  = threadIdx.x;
    const int lane = tid & 63;
    const int wv   = __builtin_amdgcn_readfirstlane(tid >> 6);  // 0..15 uniform

    // XCD-grouped remap: XCD x serves batches 4x..4x+3 (ekt/V/Q L2-resident)
    const int xcd = blockIdx.x & 7;
    const int sub = blockIdx.x >> 3;          // 0..31
    const int b   = (xcd << 2) + (sub >> 3);
    const int qr0 = ((sub & 7) << 5) + (wv << 1);   // wave's 2 q rows

    float* strip = sB + (wv << 9);   // 512 floats, wave-private

    // score-time strip: Eq rows at [0..256), w copy at [256..384)
    if (lane < 32) *(float4*)&strip[256 + (lane << 2)] = ((const float4*)w_g)[lane];
    {
        const float* qb = q_g + (size_t)(b * 256 + qr0) * 128;
        int r = lane >> 5, c = lane & 31;                 // 64 float4 = [2][128]
        float4 qv = *(const float4*)(qb + (r << 7) + (c << 2));
        float4 E;
        E.x = __builtin_amdgcn_exp2f(C2 * qv.x);
        E.y = __builtin_amdgcn_exp2f(C2 * qv.y);
        E.z = __builtin_amdgcn_exp2f(C2 * qv.z);
        E.w = __builtin_amdgcn_exp2f(C2 * qv.w);
        *(float4*)&strip[(r << 7) + (c << 2)] = E;
    }

    // stage ekt[b] (128 KB) async: 8 x 1KB chunks per wave
    {
        const float* ekb = ekt + (size_t)b * 32768;
        #pragma unroll
        for (int c = 0; c < 8; ++c) {
            int chunk = (wv << 3) + c;                    // 0..127
            stage16(ekb + (chunk << 8) + (lane << 2), kbuf + (chunk << 8));
        }
    }
    __syncthreads();    // the only barrier: drains stage + publishes nothing else needed

    // ---- score: g outer, t inner; 8 accumulators [t][r] ----
    float s[4][2];
    #pragma unroll
    for (int t = 0; t < 4; ++t) { s[t][0] = 0.f; s[t][1] = 0.f; }

    #pragma unroll 4
    for (int g = 0; g < 32; ++g) {
        float4 w4 = *(const float4*)&strip[256 + (g << 2)];     // bcast
        float4 e0 = *(const float4*)&strip[g << 2];
        float4 e1 = *(const float4*)&strip[128 + (g << 2)];
        #pragma unroll
        for (int t = 0; t < 4; ++t) {
            float4 k4 = *(const float4*)&kbuf[(t << 13) + (g << 8) + (lane << 2)];
            #define RB(E, S)                                                   \
            {                                                                  \
                float d0 = fmaf(E.x, k4.x, 1.f), d1 = fmaf(E.y, k4.y, 1.f);    \
                float d2 = fmaf(E.z, k4.z, 1.f), d3 = fmaf(E.w, k4.w, 1.f);    \
                float P01 = d0 * d1, P23 = d2 * d3;                            \
                float N01 = fmaf(w4.x, d1, w4.y * d0);                         \
                float N23 = fmaf(w4.z, d3, w4.w * d2);                         \
                float num = fmaf(N01, P23, N23 * P01);                         \
                S = fmaf(num, __builtin_amdgcn_rcpf(P01 * P23), S);            \
            }
            RB(e0, s[t][0])
            RB(e1, s[t][1])
            #undef RB
        }
    }

    // ---- softmax per row in registers (lane holds k = 64t+lane) ----
    // attn overlays the strip: row r at [r*256 .. r*256+256) (Eq/w dead for own wave)
    #pragma unroll
    for (int r = 0; r < 2; ++r) {
        float x0 = -C2 * s[0][r], x1 = -C2 * s[1][r];
        float x2 = -C2 * s[2][r], x3 = -C2 * s[3][r];
        float m = fmaxf(fmaxf(x0, x1), fmaxf(x2, x3));
        #pragma unroll
        for (int off = 32; off; off >>= 1) m = fmaxf(m, __shfl_xor(m, off));
        float e0 = __builtin_amdgcn_exp2f(x0 - m);
        float e1 = __builtin_amdgcn_exp2f(x1 - m);
        float e2 = __builtin_amdgcn_exp2f(x2 - m);
        float e3 = __builtin_amdgcn_exp2f(x3 - m);
        float sum = (e0 + e1) + (e2 + e3);
        #pragma unroll
        for (int off = 32; off; off >>= 1) sum += __shfl_xor(sum, off);
        float inv = __builtin_amdgcn_rcpf(sum);
        strip[(r << 8) + lane]       = e0 * inv;   // own-wave ds ordering
        strip[(r << 8) + 64 + lane]  = e1 * inv;
        strip[(r << 8) + 128 + lane] = e2 * inv;
        strip[(r << 8) + 192 + lane] = e3 * inv;
    }

    // ---- PV: lane = h-pair; V from global (L1/L2-hot); attn strip bcast ----
    float2 o0, o1;
    o0.x = o0.y = o1.x = o1.y = 0.f;
    const float2* vp = (const float2*)(v_g + (size_t)b * 32768) + lane;
    #pragma unroll 8
    for (int j4 = 0; j4 < 64; ++j4) {
        float4 a0 = *(const float4*)(strip + (j4 << 2));
        float4 a1 = *(const float4*)(strip + 256 + (j4 << 2));
        #pragma unroll
        for (int i = 0; i < 4; ++i) {
            float2 v2 = vp[((j4 << 2) + i) << 6];
            float c0 = (&a0.x)[i], c1 = (&a1.x)[i];
            o0.x = fmaf(c0, v2.x, o0.x); o0.y = fmaf(c0, v2.y, o0.y);
            o1.x = fmaf(c1, v2.x, o1.x); o1.y = fmaf(c1, v2.y, o1.y);
        }
    }

    float* ob = out + (size_t)(b * 256 + qr0) * 128 + (lane << 1);
    *(float2*)(ob)       = o0;
    *(float2*)(ob + 128) = o1;
}

extern "C" void kernel_launch(void* const* d_in, const int* in_sizes, int n_in,
                              void* d_out, int out_size, void* d_ws, size_t ws_size,
                              hipStream_t stream) {
    const float* q = (const float*)d_in[0];
    const float* k = (const float*)d_in[1];
    const float* v = (const float*)d_in[2];
    const float* w = (const float*)d_in[3];
    float* out = (float*)d_out;
    float* ekt = (float*)d_ws;                 // 4 MB
    addattn_prep<<<512, 512, 0, stream>>>(k, ekt);
    addattn_kernel<<<256, 1024, 0, stream>>>(q, ekt, v, w, out);
}

// Round 18
// 42.706 us; speedup vs baseline: 1.2413x; 1.2413x over previous
//
#include <hip/hip_runtime.h>
#include <math.h>

#define C2 2.8853900817779268f   // 2*log2(e)

// single fused kernel: 256 blocks x 512 thr (8 waves x 4 q rows), 1 block/CU.
// Stage: raw K[b] -> exp2 -> rotation-swizzled kbuf (in-block, no prep kernel).
// Score: g-outer/t-inner over all-resident K; operands from wave-private strip.
// ONE barrier. attn overlays strip (wave-private) -> softmax/PV barrier-free.
__global__ __launch_bounds__(512) void addattn_kernel(
    const float* __restrict__ q_g, const float* __restrict__ k_g,
    const float* __restrict__ v_g, const float* __restrict__ w_g,
    float* __restrict__ out)
{
    __shared__ float kbuf[32768];   // 128 KB: Ek[t4][g32][rot64][hi4], rot=(k64+g)&63
    __shared__ float sB[8192];      //  32 KB: 8 waves x 1024f strip: Eq[4][128]|w[128] -> attn[4][256]

    const int tid  = threadIdx.x;
    const int lane = tid & 63;
    const int wv   = __builtin_amdgcn_readfirstlane(tid >> 6);  // 0..7 uniform

    // XCD-grouped remap: XCD x serves batches 4x..4x+3 (K/V/Q L2-resident)
    const int xcd = blockIdx.x & 7;
    const int sub = blockIdx.x >> 3;          // 0..31
    const int b   = (xcd << 2) + (sub >> 3);
    const int qr0 = ((sub & 7) << 5) + (wv << 2);   // wave's 4 q rows

    float* strip = sB + (wv << 10);   // 1024 floats, wave-private

    // ---- strip: w copy at [512..640), Eq[4][128] at [0..512) ----
    if (lane < 32) *(float4*)&strip[512 + (lane << 2)] = ((const float4*)w_g)[lane];
    {
        const float* qb = q_g + (size_t)(b * 256 + qr0) * 128;
        #pragma unroll
        for (int j = 0; j < 2; ++j) {
            int f = lane + (j << 6);
            int r = f >> 5, c = f & 31;
            float4 qv = *(const float4*)(qb + (r << 7) + (c << 2));
            float4 E;
            E.x = __builtin_amdgcn_exp2f(C2 * qv.x);
            E.y = __builtin_amdgcn_exp2f(C2 * qv.y);
            E.z = __builtin_amdgcn_exp2f(C2 * qv.z);
            E.w = __builtin_amdgcn_exp2f(C2 * qv.w);
            *(float4*)&strip[(r << 7) + (c << 2)] = E;
        }
    }

    // ---- stage K[b]: load -> exp2 -> rotation-swizzled kbuf (conflict-free) ----
    {
        const float4* kg4 = (const float4*)(k_g + (size_t)b * 32768);
        #pragma unroll
        for (int j = 0; j < 16; ++j) {
            int f = tid + (j << 9);            // 0..8191 float4s
            float4 kv = kg4[f];
            int k = f >> 5, g = f & 31;
            float4 E;
            E.x = __builtin_amdgcn_exp2f(C2 * kv.x);
            E.y = __builtin_amdgcn_exp2f(C2 * kv.y);
            E.z = __builtin_amdgcn_exp2f(C2 * kv.z);
            E.w = __builtin_amdgcn_exp2f(C2 * kv.w);
            int rot = ((k & 63) + g) & 63;
            *(float4*)&kbuf[((k >> 6) << 13) + (g << 8) + (rot << 2)] = E;
        }
    }
    __syncthreads();    // the only barrier

    // ---- score: g outer, t inner; 16 accumulators [t][r] ----
    float s[4][4];
    #pragma unroll
    for (int t = 0; t < 4; ++t)
        #pragma unroll
        for (int r = 0; r < 4; ++r) s[t][r] = 0.f;

    #pragma unroll 4
    for (int g = 0; g < 32; ++g) {
        float4 w4 = *(const float4*)&strip[512 + (g << 2)];   // bcast
        float4 e0 = *(const float4*)&strip[g << 2];
        float4 e1 = *(const float4*)&strip[128 + (g << 2)];
        float4 e2 = *(const float4*)&strip[256 + (g << 2)];
        float4 e3 = *(const float4*)&strip[384 + (g << 2)];
        const int rot = (((lane + g) & 63) << 2) + (g << 8);
        #pragma unroll
        for (int t = 0; t < 4; ++t) {
            float4 k4 = *(const float4*)&kbuf[(t << 13) + rot];
            #define RB(E, S)                                                   \
            {                                                                  \
                float d0 = fmaf(E.x, k4.x, 1.f), d1 = fmaf(E.y, k4.y, 1.f);    \
                float d2 = fmaf(E.z, k4.z, 1.f), d3 = fmaf(E.w, k4.w, 1.f);    \
                float P01 = d0 * d1, P23 = d2 * d3;                            \
                float N01 = fmaf(w4.x, d1, w4.y * d0);                         \
                float N23 = fmaf(w4.z, d3, w4.w * d2);                         \
                float num = fmaf(N01, P23, N23 * P01);                         \
                S = fmaf(num, __builtin_amdgcn_rcpf(P01 * P23), S);            \
            }
            RB(e0, s[t][0])
            RB(e1, s[t][1])
            RB(e2, s[t][2])
            RB(e3, s[t][3])
            #undef RB
        }
    }

    // ---- softmax per row (lane holds k = 64t+lane); attn overlays strip ----
    #pragma unroll
    for (int r = 0; r < 4; ++r) {
        float x0 = -C2 * s[0][r], x1 = -C2 * s[1][r];
        float x2 = -C2 * s[2][r], x3 = -C2 * s[3][r];
        float m = fmaxf(fmaxf(x0, x1), fmaxf(x2, x3));
        #pragma unroll
        for (int off = 32; off; off >>= 1) m = fmaxf(m, __shfl_xor(m, off));
        float e0 = __builtin_amdgcn_exp2f(x0 - m);
        float e1 = __builtin_amdgcn_exp2f(x1 - m);
        float e2 = __builtin_amdgcn_exp2f(x2 - m);
        float e3 = __builtin_amdgcn_exp2f(x3 - m);
        float sum = (e0 + e1) + (e2 + e3);
        #pragma unroll
        for (int off = 32; off; off >>= 1) sum += __shfl_xor(sum, off);
        float inv = __builtin_amdgcn_rcpf(sum);
        strip[(r << 8) + lane]       = e0 * inv;   // own-wave ds ordering
        strip[(r << 8) + 64 + lane]  = e1 * inv;
        strip[(r << 8) + 128 + lane] = e2 * inv;
        strip[(r << 8) + 192 + lane] = e3 * inv;
    }

    // ---- PV: lane = h-pair (h = 2*lane, 2*lane+1); V global (L1/L2-hot) ----
    float2 o0, o1, o2, o3;
    o0.x = o0.y = o1.x = o1.y = 0.f;
    o2.x = o2.y = o3.x = o3.y = 0.f;
    const float2* vp = (const float2*)(v_g + (size_t)b * 32768) + lane;
    #pragma unroll 4
    for (int j4 = 0; j4 < 64; ++j4) {
        float4 a0 = *(const float4*)(strip + (j4 << 2));          // row bcasts
        float4 a1 = *(const float4*)(strip + 256 + (j4 << 2));
        float4 a2 = *(const float4*)(strip + 512 + (j4 << 2));
        float4 a3 = *(const float4*)(strip + 768 + (j4 << 2));
        #pragma unroll
        for (int i = 0; i < 4; ++i) {
            float2 v2 = vp[((j4 << 2) + i) << 6];                 // 512B coalesced
            float c0 = (&a0.x)[i], c1 = (&a1.x)[i], c2 = (&a2.x)[i], c3 = (&a3.x)[i];
            o0.x = fmaf(c0, v2.x, o0.x); o0.y = fmaf(c0, v2.y, o0.y);
            o1.x = fmaf(c1, v2.x, o1.x); o1.y = fmaf(c1, v2.y, o1.y);
            o2.x = fmaf(c2, v2.x, o2.x); o2.y = fmaf(c2, v2.y, o2.y);
            o3.x = fmaf(c3, v2.x, o3.x); o3.y = fmaf(c3, v2.y, o3.y);
        }
    }

    float* ob = out + (size_t)(b * 256 + qr0) * 128 + (lane << 1);
    *(float2*)(ob)       = o0;
    *(float2*)(ob + 128) = o1;
    *(float2*)(ob + 256) = o2;
    *(float2*)(ob + 384) = o3;
}

extern "C" void kernel_launch(void* const* d_in, const int* in_sizes, int n_in,
                              void* d_out, int out_size, void* d_ws, size_t ws_size,
                              hipStream_t stream) {
    const float* q = (const float*)d_in[0];
    const float* k = (const float*)d_in[1];
    const float* v = (const float*)d_in[2];
    const float* w = (const float*)d_in[3];
    float* out = (float*)d_out;
    addattn_kernel<<<256, 512, 0, stream>>>(q, k, v, w, out);
}